// Round 11
// baseline (247.090 us; speedup 1.0000x reference)
//
#include <hip/hip_runtime.h>
#include <math.h>

#define B_    1024
#define DE    200
#define DR    200
#define NFC   32
#define LFC   9
#define LL    192          // DE - LFC + 1
#define FC1LEN 288         // NFC*LFC
#define FCLEN 6144         // NFC*LL
#define NENT  100000
#define EPSI  1e-5f
#define KPAD  224          // 7*32 for 16x16x32 MFMA
#define NKS   7            // KPAD/32
#define YKS   192          // FCLEN/32
#define YSEG  16           // K-split for y-GEMM

// ---- workspace layout (float offsets). frag region of S slots = S*4 floats ----
#define O_S0    0
#define O_P0    64
#define O_S1    256        // s1[32], t1[32]
#define O_S2    320        // s2[200], t2[200]
#define O_P1    768        // bn1 partials 1024*32*2 -> ends 66304
#define O_RBF   66304      // r A-frags: 28672 slots = 114688 fl -> 180992
#define O_W1BF  180992     // fc1_w B-frags: 8064 slots = 32256 fl -> 213248
#define O_K     213248     // k fp32 1024x288 -> 508160
#define O_CFRAG 508160     // conv bf16 A-frags: 64*192*64 slots = 3145728 fl -> 3653888
#define O_FCWP  3653888    // fcw' B-frags: 16*192*64 slots = 786432 fl -> 4440320
#define O_CVEC  4440320    // c[200] -> 4440576
#define O_PART  4440576    // ygemm partials 16*1024*200 = 3276800 fl -> 7717376
#define O_Y     7717376    // y 1024x200 -> 7922176
#define O_ABF   7922176    // A bf16 frags: 28672 slots = 114688 fl -> 8036864 (32.1 MB)

typedef __attribute__((ext_vector_type(8))) short bf16x8;
typedef __attribute__((ext_vector_type(4))) float f32x4;

__device__ __forceinline__ float sigm(float x){
  return __fdividef(1.0f, 1.0f + __expf(-x));
}

__device__ __forceinline__ unsigned short f2bf(float f){
  unsigned int u = __float_as_uint(f);
  u = (u + 0x7FFFu + ((u >> 16) & 1u)) >> 16;   // RNE
  return (unsigned short)u;
}

__device__ __forceinline__ bf16x8 pack8v(f32x4 f0, f32x4 f1){
  bf16x8 o;
  o[0]=(short)f2bf(f0[0]); o[1]=(short)f2bf(f0[1]); o[2]=(short)f2bf(f0[2]); o[3]=(short)f2bf(f0[3]);
  o[4]=(short)f2bf(f1[0]); o[5]=(short)f2bf(f1[1]); o[6]=(short)f2bf(f1[2]); o[7]=(short)f2bf(f1[3]);
  return o;
}

// ---------- pack r (A-frags) + fc1_w (B-frags) + BN0 partials, fused ----------
__global__ void k_pack0(const float* __restrict__ r, const float* __restrict__ w,
                        const float* __restrict__ e1, float* __restrict__ ws){
  __shared__ float ss[256], sq[256];
  int blk = blockIdx.x;
  if (blk < 112){
    int s = blk*256 + threadIdx.x;        // 28672 slots exact
    int lane = s & 63;
    int ks = (s >> 6) % NKS;
    int mtile = (s >> 6) / NKS;
    int m = mtile*16 + (lane & 15);
    int k0 = ks*32 + (lane >> 4)*8;
    unsigned short o8[8];
    #pragma unroll
    for (int j = 0; j < 8; ++j){
      int k = k0 + j;
      o8[j] = f2bf((k < DR) ? r[m*DR + k] : 0.f);
    }
    *(bf16x8*)((unsigned short*)(ws + O_RBF) + (size_t)s*8) = *(bf16x8*)o8;
  } else if (blk < 144){
    int s = (blk-112)*256 + threadIdx.x;  // 8064 slots (guarded)
    if (s >= 18*NKS*64) return;
    int lane = s & 63;
    int ks = (s >> 6) % NKS;
    int ntile = (s >> 6) / NKS;
    int n = ntile*16 + (lane & 15);       // < 288
    int k0 = ks*32 + (lane >> 4)*8;
    unsigned short o8[8];
    #pragma unroll
    for (int j = 0; j < 8; ++j){
      int k = k0 + j;
      o8[j] = f2bf((k < DR) ? w[(size_t)n*DR + k] : 0.f);
    }
    *(bf16x8*)((unsigned short*)(ws + O_W1BF) + (size_t)s*8) = *(bf16x8*)o8;
  } else {
    // BN0 partials (64 blocks)
    int bb = blk - 144, tid = threadIdx.x;
    float a = 0.f, b = 0.f;
    for (int i = bb*256 + tid; i < B_*DE; i += 64*256){
      float v = e1[i]; a += v; b += v*v;
    }
    ss[tid]=a; sq[tid]=b; __syncthreads();
    for (int s=128; s>0; s>>=1){
      if (tid < s){ ss[tid]+=ss[tid+s]; sq[tid]+=sq[tid+s]; }
      __syncthreads();
    }
    if (tid==0){ ws[O_P0+2*bb]=ss[0]; ws[O_P0+2*bb+1]=sq[0]; }
  }
}

__global__ void k_bn0_final(const float* __restrict__ g, const float* __restrict__ bt,
                            float* __restrict__ ws){
  int tid = threadIdx.x;
  float a = ws[O_P0+2*tid], b = ws[O_P0+2*tid+1];
  for (int o=32; o>0; o>>=1){ a += __shfl_down(a,o); b += __shfl_down(b,o); }
  if (tid==0){
    float n = (float)(B_*DE);
    float m = a/n, v = b/n - m*m;
    float s = rsqrtf(v + EPSI) * g[0];
    ws[O_S0]   = s;
    ws[O_S0+1] = bt[0] - m*s;
  }
}

// ---------- FC1 via MFMA ----------
__global__ void k_fc1m(const float* __restrict__ bias, float* __restrict__ ws){
  const unsigned short* Rb = (const unsigned short*)(ws + O_RBF);
  const unsigned short* Wb = (const unsigned short*)(ws + O_W1BF);
  int mt = blockIdx.x;        // 0..15
  int nt = blockIdx.y;        // 0..17
  int lane = threadIdx.x;
  int lr = lane & 15, lg = lane >> 4;
  f32x4 acc[4] = {};
  #pragma unroll
  for (int ks = 0; ks < NKS; ++ks){
    bf16x8 b = *(const bf16x8*)(Wb + ((size_t)(nt*NKS + ks)*64 + lane)*8);
    #pragma unroll
    for (int mf = 0; mf < 4; ++mf){
      bf16x8 a = *(const bf16x8*)(Rb + ((size_t)((mt*4+mf)*NKS + ks)*64 + lane)*8);
      acc[mf] = __builtin_amdgcn_mfma_f32_16x16x32_bf16(a, b, acc[mf], 0, 0, 0);
    }
  }
  int col = nt*16 + lr;
  float bv = bias[col];
  #pragma unroll
  for (int mf = 0; mf < 4; ++mf){
    int row = mt*64 + mf*16 + lg*4;
    #pragma unroll
    for (int r = 0; r < 4; ++r)
      ws[O_K + (size_t)(row + r)*FC1LEN + col] = acc[mf][r] + bv;
  }
}

// ---------- conv (BN0 on the fly) -> bf16 A-frag layout + bn1 partials ----------
__global__ void k_conv(const float* __restrict__ e1, float* __restrict__ ws){
  __shared__ float xs[DE];
  __shared__ float kf[FC1LEN];
  int b = blockIdx.x, tid = threadIdx.x;
  float s0v = ws[O_S0], t0v = ws[O_S0+1];
  for (int d = tid; d < DE;     d += 256) xs[d] = e1[b*DE + d]*s0v + t0v;
  for (int i = tid; i < FC1LEN; i += 256) kf[i] = ws[O_K + (size_t)b*FC1LEN + i];
  __syncthreads();
  unsigned short* Cf = (unsigned short*)(ws + O_CFRAG);
  int f = tid >> 3, sub = tid & 7;
  int mtile = b >> 4, mlan = b & 15;
  float kr[LFC];
  #pragma unroll
  for (int j = 0; j < LFC; ++j) kr[j] = kf[f*LFC + j];
  float sum = 0.f, sq = 0.f;
  #pragma unroll
  for (int g = 0; g < 3; ++g){
    unsigned short o8[8];
    int l0 = sub*24 + g*8;
    #pragma unroll
    for (int t = 0; t < 8; ++t){
      int l = l0 + t;
      float acc = 0.f;
      #pragma unroll
      for (int j = 0; j < LFC; ++j) acc += xs[l+j]*kr[j];
      o8[t] = f2bf(acc);
      sum += acc; sq += acc*acc;
    }
    int k0 = f*LL + l0;
    int ks = k0 >> 5;
    int lane_w = ((k0 >> 3) & 3)*16 + mlan;
    size_t slot = (size_t)(mtile*YKS + ks)*64 + lane_w;
    *(bf16x8*)(Cf + slot*8) = *(bf16x8*)o8;
  }
  for (int o = 1; o < 8; o <<= 1){ sum += __shfl_xor(sum,o); sq += __shfl_xor(sq,o); }
  if (sub == 0){
    ws[O_P1 + (b*NFC + f)*2    ] = sum;
    ws[O_P1 + (b*NFC + f)*2 + 1] = sq;
  }
}

__global__ void k_bn1_final(const float* __restrict__ g, const float* __restrict__ bt,
                            float* __restrict__ ws){
  __shared__ float ss[256], sq[256];
  int f = blockIdx.x, tid = threadIdx.x;
  float a = 0.f, b = 0.f;
  for (int i = tid; i < B_; i += 256){
    a += ws[O_P1 + (i*NFC + f)*2];
    b += ws[O_P1 + (i*NFC + f)*2 + 1];
  }
  ss[tid]=a; sq[tid]=b; __syncthreads();
  for (int s=128; s>0; s>>=1){
    if (tid < s){ ss[tid]+=ss[tid+s]; sq[tid]+=sq[tid+s]; }
    __syncthreads();
  }
  if (tid==0){
    float n = (float)(B_*LL);
    float m = ss[0]/n, v = sq[0]/n - m*m;
    float s = rsqrtf(v + EPSI) * g[f];
    ws[O_S1 + f]       = s;
    ws[O_S1 + NFC + f] = bt[f] - m*s;
  }
}

// ---------- pack fcw*s1[f] into B-frag layout + cvec, fused ----------
__global__ void k_fcwp_cvec(const float* __restrict__ fcw, const float* __restrict__ fcb,
                            float* __restrict__ ws){
  __shared__ float shm[256];
  int blk = blockIdx.x;
  if (blk < 768){
    int s = blk*256 + threadIdx.x;   // 196608 slots
    int lane = s & 63;
    int ks = (s >> 6) % YKS;
    int ntile = (s >> 6) / YKS;
    int n = ntile*16 + (lane & 15);         // < 256
    int k0 = ks*32 + (lane >> 4)*8;         // < 6144
    int f = (k0 >> 6) / 3;                  // k0/192
    float sc = ws[O_S1 + f];
    unsigned short o8[8];
    if (n < DE){
      const float* p = fcw + (size_t)n*FCLEN + k0;
      float4 f0 = *(const float4*)p;
      float4 f1 = *(const float4*)(p + 4);
      o8[0]=f2bf(f0.x*sc); o8[1]=f2bf(f0.y*sc); o8[2]=f2bf(f0.z*sc); o8[3]=f2bf(f0.w*sc);
      o8[4]=f2bf(f1.x*sc); o8[5]=f2bf(f1.y*sc); o8[6]=f2bf(f1.z*sc); o8[7]=f2bf(f1.w*sc);
    } else {
      #pragma unroll
      for (int j = 0; j < 8; ++j) o8[j] = 0;
    }
    *(bf16x8*)((unsigned short*)(ws + O_FCWP) + (size_t)s*8) = *(bf16x8*)o8;
  } else {
    // cvec: c[o] = sum_i t1[f(i)]*fcw[o,i] + fc_b[o]
    __shared__ float t1s[NFC];
    int o = blk - 768, tid = threadIdx.x;
    if (tid < NFC) t1s[tid] = ws[O_S1 + NFC + tid];
    __syncthreads();
    float acc = 0.f;
    for (int i = tid; i < FCLEN; i += 256)
      acc += fcw[(size_t)o*FCLEN + i] * t1s[i/LL];
    shm[tid] = acc; __syncthreads();
    for (int s=128; s>0; s>>=1){
      if (tid < s) shm[tid] += shm[tid+s];
      __syncthreads();
    }
    if (tid==0) ws[O_CVEC + o] = shm[0] + fcb[o];
  }
}

// ---------- y-GEMM via MFMA, both sides frag-coalesced, 16-way K-split ----------
__global__ __launch_bounds__(256) void k_ygemm_m(float* __restrict__ ws){
  const unsigned short* Cb = (const unsigned short*)(ws + O_CFRAG);
  const unsigned short* Wb = (const unsigned short*)(ws + O_FCWP);
  int mt = blockIdx.x;      // 0..15
  int seg = blockIdx.y;     // 0..15
  int tid = threadIdx.x;
  int lane = tid & 63, wid = tid >> 6;
  int lr = lane & 15, lg = lane >> 4;
  f32x4 acc[4][4] = {};     // [mf][nf], nt = wid*4+nf
  #pragma unroll 4
  for (int ksl = 0; ksl < 12; ++ksl){
    int ks = seg*12 + ksl;
    bf16x8 a[4], bfr[4];
    #pragma unroll
    for (int mf = 0; mf < 4; ++mf)
      a[mf] = *(const bf16x8*)(Cb + ((size_t)((mt*4+mf)*YKS + ks)*64 + lane)*8);
    #pragma unroll
    for (int nf = 0; nf < 4; ++nf){
      int nt = wid*4 + nf;
      bfr[nf] = *(const bf16x8*)(Wb + ((size_t)(nt*YKS + ks)*64 + lane)*8);
    }
    #pragma unroll
    for (int mf = 0; mf < 4; ++mf)
      #pragma unroll
      for (int nf = 0; nf < 4; ++nf)
        acc[mf][nf] = __builtin_amdgcn_mfma_f32_16x16x32_bf16(a[mf], bfr[nf], acc[mf][nf], 0, 0, 0);
  }
  float* part = ws + O_PART + (size_t)seg*(B_*DE);
  #pragma unroll
  for (int nf = 0; nf < 4; ++nf){
    int col = (wid*4 + nf)*16 + lr;
    if (col < DE){
      #pragma unroll
      for (int mf = 0; mf < 4; ++mf){
        int row = mt*64 + mf*16 + lg*4;
        #pragma unroll
        for (int r = 0; r < 4; ++r)
          part[(size_t)(row + r)*DE + col] = acc[mf][nf][r];
      }
    }
  }
}

__global__ void k_yreduce(float* __restrict__ ws){
  int i = blockIdx.x*256 + threadIdx.x;   // 204800
  int o = i % DE;
  float y = ws[O_CVEC + o];
  #pragma unroll
  for (int s = 0; s < YSEG; ++s) y += ws[O_PART + (size_t)s*(B_*DE) + i];
  ws[O_Y + i] = y;
}

// ---------- BN2 stats ----------
__global__ void k_bn2(const float* __restrict__ g, const float* __restrict__ bt,
                      float* __restrict__ ws){
  __shared__ float ss[256], sq[256];
  int o = blockIdx.x, tid = threadIdx.x;
  float a = 0.f, b = 0.f;
  for (int i = tid; i < B_; i += 256){
    float v = ws[O_Y + i*DE + o];
    a += v; b += v*v;
  }
  ss[tid]=a; sq[tid]=b; __syncthreads();
  for (int s=128; s>0; s>>=1){
    if (tid < s){ ss[tid]+=ss[tid+s]; sq[tid]+=sq[tid+s]; }
    __syncthreads();
  }
  if (tid==0){
    float n = (float)B_;
    float m = ss[0]/n, v = sq[0]/n - m*m;
    float s = rsqrtf(v + EPSI) * g[o];
    ws[O_S2 + o]      = s;
    ws[O_S2 + DE + o] = bt[o] - m*s;
  }
}

// ---------- BN2-apply + ReLU + bf16 A-frags ----------
__global__ void k_abf(float* __restrict__ ws){
  int s = blockIdx.x*256 + threadIdx.x;   // 28672 slots exact
  int lane = s & 63;
  int ks = (s >> 6) % NKS;
  int mtile = (s >> 6) / NKS;
  int m = mtile*16 + (lane & 15);
  int k0 = ks*32 + (lane >> 4)*8;
  unsigned short o8[8];
  #pragma unroll
  for (int j = 0; j < 8; ++j){
    int k = k0 + j;
    float v = 0.f;
    if (k < DE){
      float y = ws[O_Y + m*DE + k];
      v = fmaxf(y*ws[O_S2 + k] + ws[O_S2 + DE + k], 0.f);
    }
    o8[j] = f2bf(v);
  }
  *(bf16x8*)((unsigned short*)(ws + O_ABF) + (size_t)s*8) = *(bf16x8*)o8;
}

// ---------- scores GEMM: 2 m-halves x 391 col-stripes (load-balanced), ----------
// E-resident regs (nt loads), LDS-transpose epilogue, 1KB nt row stores.
__global__ __launch_bounds__(256, 2) void k_scores(const float* __restrict__ E,
                                                   const float* __restrict__ bias,
                                                   const float* __restrict__ ws,
                                                   float* __restrict__ out){
  __shared__ float tile[64*256];          // 64 KB
  const unsigned short* Abf = (const unsigned short*)(ws + O_ABF);
  int wgid = blockIdx.x;                  // 782: identity, ns-fastest
  int mh = wgid / 391, ns = wgid - mh*391;
  int tid = threadIdx.x;
  int lane = tid & 63, wid = tid >> 6;
  int lr = lane & 15, lg = lane >> 4;

  // ---- E resident: 4 n-tiles x 7 ks, fp32 -> bf16 once (nontemporal reads) ----
  bf16x8 ebf[4][7];
  float bv[4];
  #pragma unroll
  for (int nf = 0; nf < 4; ++nf){
    int col = ns*256 + wid*64 + nf*16 + lr;
    int nc = (col < NENT) ? col : (NENT-1);
    bv[nf] = bias[nc];
    const float* ep = E + (size_t)nc*DE;
    #pragma unroll
    for (int ks = 0; ks < NKS; ++ks){
      int k0 = ks*32 + lg*8;
      if (k0 + 8 <= DE){
        f32x4 f0 = __builtin_nontemporal_load((const f32x4*)(ep + k0));
        f32x4 f1 = __builtin_nontemporal_load((const f32x4*)(ep + k0 + 4));
        ebf[nf][ks] = pack8v(f0, f1);
      } else {
        ebf[nf][ks] = (bf16x8){0,0,0,0,0,0,0,0};
      }
    }
  }

  const unsigned short* aBase = Abf + lane*8;
  int col0 = ns*256;
  #pragma unroll 1
  for (int t = 0; t < 8; ++t){
    int tt = mh*8 + t;
    const unsigned short* ap = aBase + (size_t)tt*1792*8;
    bf16x8 aC[4], aN[4];
    #pragma unroll
    for (int mf = 0; mf < 4; ++mf) aC[mf] = *(const bf16x8*)(ap + (size_t)(mf*NKS)*512);
    f32x4 acc[4][4] = {};
    #pragma unroll
    for (int ks = 0; ks < NKS; ++ks){
      if (ks < NKS-1){
        #pragma unroll
        for (int mf = 0; mf < 4; ++mf)
          aN[mf] = *(const bf16x8*)(ap + (size_t)(mf*NKS + ks + 1)*512);
      }
      #pragma unroll
      for (int mf = 0; mf < 4; ++mf)
        #pragma unroll
        for (int nf = 0; nf < 4; ++nf)
          acc[mf][nf] = __builtin_amdgcn_mfma_f32_16x16x32_bf16(aC[mf], ebf[nf][ks], acc[mf][nf], 0, 0, 0);
      #pragma unroll
      for (int mf = 0; mf < 4; ++mf) aC[mf] = aN[mf];
    }
    // ---- epilogue: sigmoid -> LDS [64 rows][256 cols] ----
    __syncthreads();                       // previous iteration's reads done
    #pragma unroll
    for (int mf = 0; mf < 4; ++mf)
      #pragma unroll
      for (int nf = 0; nf < 4; ++nf){
        int lrow = mf*16 + lg*4;
        int lcol = wid*64 + nf*16 + lr;
        #pragma unroll
        for (int r = 0; r < 4; ++r)
          tile[(lrow + r)*256 + lcol] = sigm(acc[mf][nf][r] + bv[nf]);
      }
    __syncthreads();
    // ---- wave-wide 1KB contiguous nt stores ----
    int row0 = tt*64;
    #pragma unroll
    for (int p = 0; p < 16; ++p){
      int lrow = p*4 + wid;
      int lcol = lane*4;
      f32x4 v = *(const f32x4*)&tile[lrow*256 + lcol];
      int gc = col0 + lcol;
      if (gc < NENT)
        __builtin_nontemporal_store(v, (f32x4*)&out[(size_t)(row0 + lrow)*NENT + gc]);
    }
  }
}

extern "C" void kernel_launch(void* const* d_in, const int* in_sizes, int n_in,
                              void* d_out, int out_size, void* d_ws, size_t ws_size,
                              hipStream_t stream){
  (void)in_sizes; (void)n_in; (void)out_size; (void)ws_size;
  const float* e1    = (const float*)d_in[0];
  const float* r     = (const float*)d_in[1];
  const float* fc1_w = (const float*)d_in[2];
  const float* fc1_b = (const float*)d_in[3];
  const float* fc_w  = (const float*)d_in[4];
  const float* fc_b  = (const float*)d_in[5];
  const float* E     = (const float*)d_in[6];
  const float* bE    = (const float*)d_in[7];
  const float* g0    = (const float*)d_in[8];
  const float* b0    = (const float*)d_in[9];
  const float* g1    = (const float*)d_in[10];
  const float* b1    = (const float*)d_in[11];
  const float* g2    = (const float*)d_in[12];
  const float* b2    = (const float*)d_in[13];
  float* ws  = (float*)d_ws;
  float* out = (float*)d_out;

  k_pack0     <<<208, 256, 0, stream>>>(r, fc1_w, e1, ws);
  k_bn0_final <<<1,   64,  0, stream>>>(g0, b0, ws);
  k_fc1m      <<<dim3(16,18), 64, 0, stream>>>(fc1_b, ws);
  k_conv      <<<1024,256, 0, stream>>>(e1, ws);
  k_bn1_final <<<32,  256, 0, stream>>>(g1, b1, ws);
  k_fcwp_cvec <<<968, 256, 0, stream>>>(fc_w, fc_b, ws);
  k_ygemm_m   <<<dim3(16,16), 256, 0, stream>>>(ws);
  k_yreduce   <<<800, 256, 0, stream>>>(ws);
  k_bn2       <<<200, 256, 0, stream>>>(g2, b2, ws);
  k_abf       <<<112, 256, 0, stream>>>(ws);
  k_scores    <<<782, 256, 0, stream>>>(E, bE, ws, out);
}

// Round 12
// 212.115 us; speedup vs baseline: 1.1649x; 1.1649x over previous
//
#include <hip/hip_runtime.h>
#include <math.h>

#define B_    1024
#define DE    200
#define DR    200
#define NFC   32
#define LFC   9
#define LL    192          // DE - LFC + 1
#define FC1LEN 288         // NFC*LFC
#define FCLEN 6144         // NFC*LL
#define NENT  100000
#define EPSI  1e-5f
#define KPAD  224          // 7*32 for 16x16x32 MFMA
#define NKS   7            // KPAD/32
#define YKS   192          // FCLEN/32
#define YSEG  16           // K-split for y-GEMM

// ---- workspace layout (float offsets). frag region of S slots = S*4 floats ----
#define O_S0    0
#define O_P0    64
#define O_S1    256        // s1[32], t1[32]
#define O_S2    320        // s2[200], t2[200]
#define O_P1    768        // bn1 partials 1024*32*2 -> ends 66304
#define O_RBF   66304      // r A-frags: 28672 slots = 114688 fl -> 180992
#define O_W1BF  180992     // fc1_w B-frags: 8064 slots = 32256 fl -> 213248
#define O_K     213248     // k fp32 1024x288 -> 508160
#define O_CFRAG 508160     // conv bf16 A-frags: 64*192*64 slots = 3145728 fl -> 3653888
#define O_FCWP  3653888    // fcw' B-frags: 16*192*64 slots = 786432 fl -> 4440320
#define O_CVEC  4440320    // c[200] -> 4440576
#define O_PART  4440576    // ygemm partials 16*1024*200 = 3276800 fl -> 7717376
#define O_Y     7717376    // y 1024x200 -> 7922176
#define O_ABF   7922176    // A bf16 frags: 28672 slots = 114688 fl -> 8036864 (32.1 MB)

typedef __attribute__((ext_vector_type(8))) short bf16x8;
typedef __attribute__((ext_vector_type(4))) float f32x4;

__device__ __forceinline__ float sigm(float x){
  return __fdividef(1.0f, 1.0f + __expf(-x));
}

__device__ __forceinline__ unsigned short f2bf(float f){
  unsigned int u = __float_as_uint(f);
  u = (u + 0x7FFFu + ((u >> 16) & 1u)) >> 16;   // RNE
  return (unsigned short)u;
}

__device__ __forceinline__ bf16x8 pack8v(f32x4 f0, f32x4 f1){
  bf16x8 o;
  o[0]=(short)f2bf(f0[0]); o[1]=(short)f2bf(f0[1]); o[2]=(short)f2bf(f0[2]); o[3]=(short)f2bf(f0[3]);
  o[4]=(short)f2bf(f1[0]); o[5]=(short)f2bf(f1[1]); o[6]=(short)f2bf(f1[2]); o[7]=(short)f2bf(f1[3]);
  return o;
}

// ---------- pack r (A-frags) + fc1_w (B-frags) + BN0 partials, fused ----------
__global__ void k_pack0(const float* __restrict__ r, const float* __restrict__ w,
                        const float* __restrict__ e1, float* __restrict__ ws){
  __shared__ float ss[256], sq[256];
  int blk = blockIdx.x;
  if (blk < 112){
    int s = blk*256 + threadIdx.x;        // 28672 slots exact
    int lane = s & 63;
    int ks = (s >> 6) % NKS;
    int mtile = (s >> 6) / NKS;
    int m = mtile*16 + (lane & 15);
    int k0 = ks*32 + (lane >> 4)*8;
    unsigned short o8[8];
    #pragma unroll
    for (int j = 0; j < 8; ++j){
      int k = k0 + j;
      o8[j] = f2bf((k < DR) ? r[m*DR + k] : 0.f);
    }
    *(bf16x8*)((unsigned short*)(ws + O_RBF) + (size_t)s*8) = *(bf16x8*)o8;
  } else if (blk < 144){
    int s = (blk-112)*256 + threadIdx.x;  // 8064 slots (guarded)
    if (s >= 18*NKS*64) return;
    int lane = s & 63;
    int ks = (s >> 6) % NKS;
    int ntile = (s >> 6) / NKS;
    int n = ntile*16 + (lane & 15);       // < 288
    int k0 = ks*32 + (lane >> 4)*8;
    unsigned short o8[8];
    #pragma unroll
    for (int j = 0; j < 8; ++j){
      int k = k0 + j;
      o8[j] = f2bf((k < DR) ? w[(size_t)n*DR + k] : 0.f);
    }
    *(bf16x8*)((unsigned short*)(ws + O_W1BF) + (size_t)s*8) = *(bf16x8*)o8;
  } else {
    // BN0 partials (64 blocks)
    int bb = blk - 144, tid = threadIdx.x;
    float a = 0.f, b = 0.f;
    for (int i = bb*256 + tid; i < B_*DE; i += 64*256){
      float v = e1[i]; a += v; b += v*v;
    }
    ss[tid]=a; sq[tid]=b; __syncthreads();
    for (int s=128; s>0; s>>=1){
      if (tid < s){ ss[tid]+=ss[tid+s]; sq[tid]+=sq[tid+s]; }
      __syncthreads();
    }
    if (tid==0){ ws[O_P0+2*bb]=ss[0]; ws[O_P0+2*bb+1]=sq[0]; }
  }
}

__global__ void k_bn0_final(const float* __restrict__ g, const float* __restrict__ bt,
                            float* __restrict__ ws){
  int tid = threadIdx.x;
  float a = ws[O_P0+2*tid], b = ws[O_P0+2*tid+1];
  for (int o=32; o>0; o>>=1){ a += __shfl_down(a,o); b += __shfl_down(b,o); }
  if (tid==0){
    float n = (float)(B_*DE);
    float m = a/n, v = b/n - m*m;
    float s = rsqrtf(v + EPSI) * g[0];
    ws[O_S0]   = s;
    ws[O_S0+1] = bt[0] - m*s;
  }
}

// ---------- FC1 via MFMA ----------
__global__ void k_fc1m(const float* __restrict__ bias, float* __restrict__ ws){
  const unsigned short* Rb = (const unsigned short*)(ws + O_RBF);
  const unsigned short* Wb = (const unsigned short*)(ws + O_W1BF);
  int mt = blockIdx.x;        // 0..15
  int nt = blockIdx.y;        // 0..17
  int lane = threadIdx.x;
  int lr = lane & 15, lg = lane >> 4;
  f32x4 acc[4] = {};
  #pragma unroll
  for (int ks = 0; ks < NKS; ++ks){
    bf16x8 b = *(const bf16x8*)(Wb + ((size_t)(nt*NKS + ks)*64 + lane)*8);
    #pragma unroll
    for (int mf = 0; mf < 4; ++mf){
      bf16x8 a = *(const bf16x8*)(Rb + ((size_t)((mt*4+mf)*NKS + ks)*64 + lane)*8);
      acc[mf] = __builtin_amdgcn_mfma_f32_16x16x32_bf16(a, b, acc[mf], 0, 0, 0);
    }
  }
  int col = nt*16 + lr;
  float bv = bias[col];
  #pragma unroll
  for (int mf = 0; mf < 4; ++mf){
    int row = mt*64 + mf*16 + lg*4;
    #pragma unroll
    for (int r = 0; r < 4; ++r)
      ws[O_K + (size_t)(row + r)*FC1LEN + col] = acc[mf][r] + bv;
  }
}

// ---------- conv (BN0 on the fly) -> bf16 A-frag layout + bn1 partials ----------
__global__ void k_conv(const float* __restrict__ e1, float* __restrict__ ws){
  __shared__ float xs[DE];
  __shared__ float kf[FC1LEN];
  int b = blockIdx.x, tid = threadIdx.x;
  float s0v = ws[O_S0], t0v = ws[O_S0+1];
  for (int d = tid; d < DE;     d += 256) xs[d] = e1[b*DE + d]*s0v + t0v;
  for (int i = tid; i < FC1LEN; i += 256) kf[i] = ws[O_K + (size_t)b*FC1LEN + i];
  __syncthreads();
  unsigned short* Cf = (unsigned short*)(ws + O_CFRAG);
  int f = tid >> 3, sub = tid & 7;
  int mtile = b >> 4, mlan = b & 15;
  float kr[LFC];
  #pragma unroll
  for (int j = 0; j < LFC; ++j) kr[j] = kf[f*LFC + j];
  float sum = 0.f, sq = 0.f;
  #pragma unroll
  for (int g = 0; g < 3; ++g){
    unsigned short o8[8];
    int l0 = sub*24 + g*8;
    #pragma unroll
    for (int t = 0; t < 8; ++t){
      int l = l0 + t;
      float acc = 0.f;
      #pragma unroll
      for (int j = 0; j < LFC; ++j) acc += xs[l+j]*kr[j];
      o8[t] = f2bf(acc);
      sum += acc; sq += acc*acc;
    }
    int k0 = f*LL + l0;
    int ks = k0 >> 5;
    int lane_w = ((k0 >> 3) & 3)*16 + mlan;
    size_t slot = (size_t)(mtile*YKS + ks)*64 + lane_w;
    *(bf16x8*)(Cf + slot*8) = *(bf16x8*)o8;
  }
  for (int o = 1; o < 8; o <<= 1){ sum += __shfl_xor(sum,o); sq += __shfl_xor(sq,o); }
  if (sub == 0){
    ws[O_P1 + (b*NFC + f)*2    ] = sum;
    ws[O_P1 + (b*NFC + f)*2 + 1] = sq;
  }
}

__global__ void k_bn1_final(const float* __restrict__ g, const float* __restrict__ bt,
                            float* __restrict__ ws){
  __shared__ float ss[256], sq[256];
  int f = blockIdx.x, tid = threadIdx.x;
  float a = 0.f, b = 0.f;
  for (int i = tid; i < B_; i += 256){
    a += ws[O_P1 + (i*NFC + f)*2];
    b += ws[O_P1 + (i*NFC + f)*2 + 1];
  }
  ss[tid]=a; sq[tid]=b; __syncthreads();
  for (int s=128; s>0; s>>=1){
    if (tid < s){ ss[tid]+=ss[tid+s]; sq[tid]+=sq[tid+s]; }
    __syncthreads();
  }
  if (tid==0){
    float n = (float)(B_*LL);
    float m = ss[0]/n, v = sq[0]/n - m*m;
    float s = rsqrtf(v + EPSI) * g[f];
    ws[O_S1 + f]       = s;
    ws[O_S1 + NFC + f] = bt[f] - m*s;
  }
}

// ---------- pack fcw*s1[f] into B-frag layout + cvec, fused ----------
__global__ void k_fcwp_cvec(const float* __restrict__ fcw, const float* __restrict__ fcb,
                            float* __restrict__ ws){
  __shared__ float shm[256];
  int blk = blockIdx.x;
  if (blk < 768){
    int s = blk*256 + threadIdx.x;   // 196608 slots
    int lane = s & 63;
    int ks = (s >> 6) % YKS;
    int ntile = (s >> 6) / YKS;
    int n = ntile*16 + (lane & 15);         // < 256
    int k0 = ks*32 + (lane >> 4)*8;         // < 6144
    int f = (k0 >> 6) / 3;                  // k0/192
    float sc = ws[O_S1 + f];
    unsigned short o8[8];
    if (n < DE){
      const float* p = fcw + (size_t)n*FCLEN + k0;
      float4 f0 = *(const float4*)p;
      float4 f1 = *(const float4*)(p + 4);
      o8[0]=f2bf(f0.x*sc); o8[1]=f2bf(f0.y*sc); o8[2]=f2bf(f0.z*sc); o8[3]=f2bf(f0.w*sc);
      o8[4]=f2bf(f1.x*sc); o8[5]=f2bf(f1.y*sc); o8[6]=f2bf(f1.z*sc); o8[7]=f2bf(f1.w*sc);
    } else {
      #pragma unroll
      for (int j = 0; j < 8; ++j) o8[j] = 0;
    }
    *(bf16x8*)((unsigned short*)(ws + O_FCWP) + (size_t)s*8) = *(bf16x8*)o8;
  } else {
    // cvec: c[o] = sum_i t1[f(i)]*fcw[o,i] + fc_b[o]
    __shared__ float t1s[NFC];
    int o = blk - 768, tid = threadIdx.x;
    if (tid < NFC) t1s[tid] = ws[O_S1 + NFC + tid];
    __syncthreads();
    float acc = 0.f;
    for (int i = tid; i < FCLEN; i += 256)
      acc += fcw[(size_t)o*FCLEN + i] * t1s[i/LL];
    shm[tid] = acc; __syncthreads();
    for (int s=128; s>0; s>>=1){
      if (tid < s) shm[tid] += shm[tid+s];
      __syncthreads();
    }
    if (tid==0) ws[O_CVEC + o] = shm[0] + fcb[o];
  }
}

// ---------- y-GEMM via MFMA, both sides frag-coalesced, 16-way K-split ----------
__global__ __launch_bounds__(256) void k_ygemm_m(float* __restrict__ ws){
  const unsigned short* Cb = (const unsigned short*)(ws + O_CFRAG);
  const unsigned short* Wb = (const unsigned short*)(ws + O_FCWP);
  int mt = blockIdx.x;      // 0..15
  int seg = blockIdx.y;     // 0..15
  int tid = threadIdx.x;
  int lane = tid & 63, wid = tid >> 6;
  int lr = lane & 15, lg = lane >> 4;
  f32x4 acc[4][4] = {};     // [mf][nf], nt = wid*4+nf
  #pragma unroll 4
  for (int ksl = 0; ksl < 12; ++ksl){
    int ks = seg*12 + ksl;
    bf16x8 a[4], bfr[4];
    #pragma unroll
    for (int mf = 0; mf < 4; ++mf)
      a[mf] = *(const bf16x8*)(Cb + ((size_t)((mt*4+mf)*YKS + ks)*64 + lane)*8);
    #pragma unroll
    for (int nf = 0; nf < 4; ++nf){
      int nt = wid*4 + nf;
      bfr[nf] = *(const bf16x8*)(Wb + ((size_t)(nt*YKS + ks)*64 + lane)*8);
    }
    #pragma unroll
    for (int mf = 0; mf < 4; ++mf)
      #pragma unroll
      for (int nf = 0; nf < 4; ++nf)
        acc[mf][nf] = __builtin_amdgcn_mfma_f32_16x16x32_bf16(a[mf], bfr[nf], acc[mf][nf], 0, 0, 0);
  }
  float* part = ws + O_PART + (size_t)seg*(B_*DE);
  #pragma unroll
  for (int nf = 0; nf < 4; ++nf){
    int col = (wid*4 + nf)*16 + lr;
    if (col < DE){
      #pragma unroll
      for (int mf = 0; mf < 4; ++mf){
        int row = mt*64 + mf*16 + lg*4;
        #pragma unroll
        for (int r = 0; r < 4; ++r)
          part[(size_t)(row + r)*DE + col] = acc[mf][nf][r];
      }
    }
  }
}

__global__ void k_yreduce(float* __restrict__ ws){
  int i = blockIdx.x*256 + threadIdx.x;   // 204800
  int o = i % DE;
  float y = ws[O_CVEC + o];
  #pragma unroll
  for (int s = 0; s < YSEG; ++s) y += ws[O_PART + (size_t)s*(B_*DE) + i];
  ws[O_Y + i] = y;
}

// ---------- BN2 stats ----------
__global__ void k_bn2(const float* __restrict__ g, const float* __restrict__ bt,
                      float* __restrict__ ws){
  __shared__ float ss[256], sq[256];
  int o = blockIdx.x, tid = threadIdx.x;
  float a = 0.f, b = 0.f;
  for (int i = tid; i < B_; i += 256){
    float v = ws[O_Y + i*DE + o];
    a += v; b += v*v;
  }
  ss[tid]=a; sq[tid]=b; __syncthreads();
  for (int s=128; s>0; s>>=1){
    if (tid < s){ ss[tid]+=ss[tid+s]; sq[tid]+=sq[tid+s]; }
    __syncthreads();
  }
  if (tid==0){
    float n = (float)B_;
    float m = ss[0]/n, v = sq[0]/n - m*m;
    float s = rsqrtf(v + EPSI) * g[o];
    ws[O_S2 + o]      = s;
    ws[O_S2 + DE + o] = bt[o] - m*s;
  }
}

// ---------- BN2-apply + ReLU + bf16 A-frags ----------
__global__ void k_abf(float* __restrict__ ws){
  int s = blockIdx.x*256 + threadIdx.x;   // 28672 slots exact
  int lane = s & 63;
  int ks = (s >> 6) % NKS;
  int mtile = (s >> 6) / NKS;
  int m = mtile*16 + (lane & 15);
  int k0 = ks*32 + (lane >> 4)*8;
  unsigned short o8[8];
  #pragma unroll
  for (int j = 0; j < 8; ++j){
    int k = k0 + j;
    float v = 0.f;
    if (k < DE){
      float y = ws[O_Y + m*DE + k];
      v = fmaxf(y*ws[O_S2 + k] + ws[O_S2 + DE + k], 0.f);
    }
    o8[j] = f2bf(v);
  }
  *(bf16x8*)((unsigned short*)(ws + O_ABF) + (size_t)s*8) = *(bf16x8*)o8;
}

// ---------- scores GEMM: one block per 256-col stripe, all 1024 rows ----------
// grid 391. E slice read ONCE per block (nt loads). Stores via L2 (NOT nt):
// L2 writeback merges adjacent tiles into larger sequential runs.
__global__ __launch_bounds__(256, 2) void k_scores(const float* __restrict__ E,
                                                   const float* __restrict__ bias,
                                                   const float* __restrict__ ws,
                                                   float* __restrict__ out){
  __shared__ float tile[64*256];          // 64 KB
  const unsigned short* Abf = (const unsigned short*)(ws + O_ABF);
  int ns = blockIdx.x;                    // 0..390
  int tid = threadIdx.x;
  int lane = tid & 63, wid = tid >> 6;
  int lr = lane & 15, lg = lane >> 4;

  // ---- E resident: 4 n-tiles x 7 ks, fp32 -> bf16 once (nontemporal reads) ----
  bf16x8 ebf[4][7];
  float bv[4];
  #pragma unroll
  for (int nf = 0; nf < 4; ++nf){
    int col = ns*256 + wid*64 + nf*16 + lr;
    int nc = (col < NENT) ? col : (NENT-1);
    bv[nf] = bias[nc];
    const float* ep = E + (size_t)nc*DE;
    #pragma unroll
    for (int ks = 0; ks < NKS; ++ks){
      int k0 = ks*32 + lg*8;
      if (k0 + 8 <= DE){
        f32x4 f0 = __builtin_nontemporal_load((const f32x4*)(ep + k0));
        f32x4 f1 = __builtin_nontemporal_load((const f32x4*)(ep + k0 + 4));
        ebf[nf][ks] = pack8v(f0, f1);
      } else {
        ebf[nf][ks] = (bf16x8){0,0,0,0,0,0,0,0};
      }
    }
  }

  const unsigned short* aBase = Abf + lane*8;
  int col0 = ns*256;
  #pragma unroll 1
  for (int t = 0; t < 16; ++t){
    const unsigned short* ap = aBase + (size_t)t*1792*8;
    bf16x8 aC[4], aN[4];
    #pragma unroll
    for (int mf = 0; mf < 4; ++mf) aC[mf] = *(const bf16x8*)(ap + (size_t)(mf*NKS)*512);
    f32x4 acc[4][4] = {};
    #pragma unroll
    for (int ks = 0; ks < NKS; ++ks){
      if (ks < NKS-1){
        #pragma unroll
        for (int mf = 0; mf < 4; ++mf)
          aN[mf] = *(const bf16x8*)(ap + (size_t)(mf*NKS + ks + 1)*512);
      }
      #pragma unroll
      for (int mf = 0; mf < 4; ++mf)
        #pragma unroll
        for (int nf = 0; nf < 4; ++nf)
          acc[mf][nf] = __builtin_amdgcn_mfma_f32_16x16x32_bf16(aC[mf], ebf[nf][ks], acc[mf][nf], 0, 0, 0);
      #pragma unroll
      for (int mf = 0; mf < 4; ++mf) aC[mf] = aN[mf];
    }
    // ---- epilogue: sigmoid -> LDS [64 rows][256 cols] ----
    __syncthreads();                       // previous iteration's reads done
    #pragma unroll
    for (int mf = 0; mf < 4; ++mf)
      #pragma unroll
      for (int nf = 0; nf < 4; ++nf){
        int lrow = mf*16 + lg*4;
        int lcol = wid*64 + nf*16 + lr;
        #pragma unroll
        for (int r = 0; r < 4; ++r)
          tile[(lrow + r)*256 + lcol] = sigm(acc[mf][nf][r] + bv[nf]);
      }
    __syncthreads();
    // ---- wave-wide 1KB contiguous stores (through L2 for writeback merge) ----
    int row0 = t*64;
    #pragma unroll
    for (int p = 0; p < 16; ++p){
      int lrow = p*4 + wid;
      int lcol = lane*4;
      f32x4 v = *(const f32x4*)&tile[lrow*256 + lcol];
      int gc = col0 + lcol;
      if (gc < NENT)
        *(f32x4*)&out[(size_t)(row0 + lrow)*NENT + gc] = v;
    }
  }
}

extern "C" void kernel_launch(void* const* d_in, const int* in_sizes, int n_in,
                              void* d_out, int out_size, void* d_ws, size_t ws_size,
                              hipStream_t stream){
  (void)in_sizes; (void)n_in; (void)out_size; (void)ws_size;
  const float* e1    = (const float*)d_in[0];
  const float* r     = (const float*)d_in[1];
  const float* fc1_w = (const float*)d_in[2];
  const float* fc1_b = (const float*)d_in[3];
  const float* fc_w  = (const float*)d_in[4];
  const float* fc_b  = (const float*)d_in[5];
  const float* E     = (const float*)d_in[6];
  const float* bE    = (const float*)d_in[7];
  const float* g0    = (const float*)d_in[8];
  const float* b0    = (const float*)d_in[9];
  const float* g1    = (const float*)d_in[10];
  const float* b1    = (const float*)d_in[11];
  const float* g2    = (const float*)d_in[12];
  const float* b2    = (const float*)d_in[13];
  float* ws  = (float*)d_ws;
  float* out = (float*)d_out;

  k_pack0     <<<208, 256, 0, stream>>>(r, fc1_w, e1, ws);
  k_bn0_final <<<1,   64,  0, stream>>>(g0, b0, ws);
  k_fc1m      <<<dim3(16,18), 64, 0, stream>>>(fc1_b, ws);
  k_conv      <<<1024,256, 0, stream>>>(e1, ws);
  k_bn1_final <<<32,  256, 0, stream>>>(g1, b1, ws);
  k_fcwp_cvec <<<968, 256, 0, stream>>>(fc_w, fc_b, ws);
  k_ygemm_m   <<<dim3(16,16), 256, 0, stream>>>(ws);
  k_yreduce   <<<800, 256, 0, stream>>>(ws);
  k_bn2       <<<200, 256, 0, stream>>>(g2, b2, ws);
  k_abf       <<<112, 256, 0, stream>>>(ws);
  k_scores    <<<391, 256, 0, stream>>>(E, bE, ws, out);
}

// Round 13
// 195.931 us; speedup vs baseline: 1.2611x; 1.0826x over previous
//
#include <hip/hip_runtime.h>
#include <math.h>

#define B_    1024
#define DE    200
#define DR    200
#define NFC   32
#define LFC   9
#define LL    192          // DE - LFC + 1
#define FC1LEN 288         // NFC*LFC
#define FCLEN 6144         // NFC*LL
#define NENT  100000
#define EPSI  1e-5f
#define KPAD  224          // 7*32 for 16x16x32 MFMA
#define NKS   7            // KPAD/32
#define YKS   192          // FCLEN/32
#define YSEG  16           // K-split for y-GEMM

// ---- workspace layout (float offsets). frag region of S slots = S*4 floats ----
#define O_S0    0
#define O_P0    64
#define O_S1    256        // s1[32], t1[32]
#define O_S2    320        // s2[200], t2[200]
#define O_P1    768        // bn1 partials 1024*32*2 -> ends 66304
#define O_RBF   66304      // r A-frags: 28672 slots = 114688 fl -> 180992
#define O_W1BF  180992     // fc1_w B-frags: 8064 slots = 32256 fl -> 213248
#define O_K     213248     // k fp32 1024x288 -> 508160
#define O_CFRAG 508160     // conv bf16 A-frags: 64*192*64 slots = 3145728 fl -> 3653888
#define O_FCWP  3653888    // fcw' B-frags: 16*192*64 slots = 786432 fl -> 4440320
#define O_CVEC  4440320    // c[200] -> 4440576
#define O_PART  4440576    // ygemm partials 16*1024*200 = 3276800 fl -> 7717376
#define O_Y     7717376    // y 1024x200 -> 7922176
#define O_ABF   7922176    // A bf16 frags: 28672 slots = 114688 fl -> 8036864 (32.1 MB)

typedef __attribute__((ext_vector_type(8))) short bf16x8;
typedef __attribute__((ext_vector_type(4))) float f32x4;

__device__ __forceinline__ float sigm(float x){
  return __fdividef(1.0f, 1.0f + __expf(-x));
}

__device__ __forceinline__ unsigned short f2bf(float f){
  unsigned int u = __float_as_uint(f);
  u = (u + 0x7FFFu + ((u >> 16) & 1u)) >> 16;   // RNE
  return (unsigned short)u;
}

__device__ __forceinline__ bf16x8 pack8v(f32x4 f0, f32x4 f1){
  bf16x8 o;
  o[0]=(short)f2bf(f0[0]); o[1]=(short)f2bf(f0[1]); o[2]=(short)f2bf(f0[2]); o[3]=(short)f2bf(f0[3]);
  o[4]=(short)f2bf(f1[0]); o[5]=(short)f2bf(f1[1]); o[6]=(short)f2bf(f1[2]); o[7]=(short)f2bf(f1[3]);
  return o;
}

// ---------- pack r (A-frags) + fc1_w (B-frags) + BN0 partials, fused ----------
__global__ void k_pack0(const float* __restrict__ r, const float* __restrict__ w,
                        const float* __restrict__ e1, float* __restrict__ ws){
  __shared__ float ss[256], sq[256];
  int blk = blockIdx.x;
  if (blk < 112){
    int s = blk*256 + threadIdx.x;        // 28672 slots exact
    int lane = s & 63;
    int ks = (s >> 6) % NKS;
    int mtile = (s >> 6) / NKS;
    int m = mtile*16 + (lane & 15);
    int k0 = ks*32 + (lane >> 4)*8;
    unsigned short o8[8];
    #pragma unroll
    for (int j = 0; j < 8; ++j){
      int k = k0 + j;
      o8[j] = f2bf((k < DR) ? r[m*DR + k] : 0.f);
    }
    *(bf16x8*)((unsigned short*)(ws + O_RBF) + (size_t)s*8) = *(bf16x8*)o8;
  } else if (blk < 144){
    int s = (blk-112)*256 + threadIdx.x;  // 8064 slots (guarded)
    if (s >= 18*NKS*64) return;
    int lane = s & 63;
    int ks = (s >> 6) % NKS;
    int ntile = (s >> 6) / NKS;
    int n = ntile*16 + (lane & 15);       // < 288
    int k0 = ks*32 + (lane >> 4)*8;
    unsigned short o8[8];
    #pragma unroll
    for (int j = 0; j < 8; ++j){
      int k = k0 + j;
      o8[j] = f2bf((k < DR) ? w[(size_t)n*DR + k] : 0.f);
    }
    *(bf16x8*)((unsigned short*)(ws + O_W1BF) + (size_t)s*8) = *(bf16x8*)o8;
  } else {
    // BN0 partials (64 blocks)
    int bb = blk - 144, tid = threadIdx.x;
    float a = 0.f, b = 0.f;
    for (int i = bb*256 + tid; i < B_*DE; i += 64*256){
      float v = e1[i]; a += v; b += v*v;
    }
    ss[tid]=a; sq[tid]=b; __syncthreads();
    for (int s=128; s>0; s>>=1){
      if (tid < s){ ss[tid]+=ss[tid+s]; sq[tid]+=sq[tid+s]; }
      __syncthreads();
    }
    if (tid==0){ ws[O_P0+2*bb]=ss[0]; ws[O_P0+2*bb+1]=sq[0]; }
  }
}

// ---------- FC1 via MFMA (+ BN0 finalize in the extra block column) ----------
__global__ void k_fc1m(const float* __restrict__ bias,
                       const float* __restrict__ g0, const float* __restrict__ b0,
                       float* __restrict__ ws){
  int mt = blockIdx.x;        // 0..15
  int nt = blockIdx.y;        // 0..18 (18 = bn0_final)
  int lane = threadIdx.x;
  if (nt == 18){
    if (mt == 0){
      float a = ws[O_P0+2*lane], b = ws[O_P0+2*lane+1];
      for (int o=32; o>0; o>>=1){ a += __shfl_down(a,o); b += __shfl_down(b,o); }
      if (lane==0){
        float n = (float)(B_*DE);
        float m = a/n, v = b/n - m*m;
        float s = rsqrtf(v + EPSI) * g0[0];
        ws[O_S0]   = s;
        ws[O_S0+1] = b0[0] - m*s;
      }
    }
    return;
  }
  const unsigned short* Rb = (const unsigned short*)(ws + O_RBF);
  const unsigned short* Wb = (const unsigned short*)(ws + O_W1BF);
  int lr = lane & 15, lg = lane >> 4;
  f32x4 acc[4] = {};
  #pragma unroll
  for (int ks = 0; ks < NKS; ++ks){
    bf16x8 b = *(const bf16x8*)(Wb + ((size_t)(nt*NKS + ks)*64 + lane)*8);
    #pragma unroll
    for (int mf = 0; mf < 4; ++mf){
      bf16x8 a = *(const bf16x8*)(Rb + ((size_t)((mt*4+mf)*NKS + ks)*64 + lane)*8);
      acc[mf] = __builtin_amdgcn_mfma_f32_16x16x32_bf16(a, b, acc[mf], 0, 0, 0);
    }
  }
  int col = nt*16 + lr;
  float bv = bias[col];
  #pragma unroll
  for (int mf = 0; mf < 4; ++mf){
    int row = mt*64 + mf*16 + lg*4;
    #pragma unroll
    for (int r = 0; r < 4; ++r)
      ws[O_K + (size_t)(row + r)*FC1LEN + col] = acc[mf][r] + bv;
  }
}

// ---------- conv (BN0 on the fly) -> bf16 A-frag layout + bn1 partials ----------
__global__ void k_conv(const float* __restrict__ e1, float* __restrict__ ws){
  __shared__ float xs[DE];
  __shared__ float kf[FC1LEN];
  int b = blockIdx.x, tid = threadIdx.x;
  float s0v = ws[O_S0], t0v = ws[O_S0+1];
  for (int d = tid; d < DE;     d += 256) xs[d] = e1[b*DE + d]*s0v + t0v;
  for (int i = tid; i < FC1LEN; i += 256) kf[i] = ws[O_K + (size_t)b*FC1LEN + i];
  __syncthreads();
  unsigned short* Cf = (unsigned short*)(ws + O_CFRAG);
  int f = tid >> 3, sub = tid & 7;
  int mtile = b >> 4, mlan = b & 15;
  float kr[LFC];
  #pragma unroll
  for (int j = 0; j < LFC; ++j) kr[j] = kf[f*LFC + j];
  float sum = 0.f, sq = 0.f;
  #pragma unroll
  for (int g = 0; g < 3; ++g){
    unsigned short o8[8];
    int l0 = sub*24 + g*8;
    #pragma unroll
    for (int t = 0; t < 8; ++t){
      int l = l0 + t;
      float acc = 0.f;
      #pragma unroll
      for (int j = 0; j < LFC; ++j) acc += xs[l+j]*kr[j];
      o8[t] = f2bf(acc);
      sum += acc; sq += acc*acc;
    }
    int k0 = f*LL + l0;
    int ks = k0 >> 5;
    int lane_w = ((k0 >> 3) & 3)*16 + mlan;
    size_t slot = (size_t)(mtile*YKS + ks)*64 + lane_w;
    *(bf16x8*)(Cf + slot*8) = *(bf16x8*)o8;
  }
  for (int o = 1; o < 8; o <<= 1){ sum += __shfl_xor(sum,o); sq += __shfl_xor(sq,o); }
  if (sub == 0){
    ws[O_P1 + (b*NFC + f)*2    ] = sum;
    ws[O_P1 + (b*NFC + f)*2 + 1] = sq;
  }
}

__global__ void k_bn1_final(const float* __restrict__ g, const float* __restrict__ bt,
                            float* __restrict__ ws){
  __shared__ float ss[256], sq[256];
  int f = blockIdx.x, tid = threadIdx.x;
  float a = 0.f, b = 0.f;
  for (int i = tid; i < B_; i += 256){
    a += ws[O_P1 + (i*NFC + f)*2];
    b += ws[O_P1 + (i*NFC + f)*2 + 1];
  }
  ss[tid]=a; sq[tid]=b; __syncthreads();
  for (int s=128; s>0; s>>=1){
    if (tid < s){ ss[tid]+=ss[tid+s]; sq[tid]+=sq[tid+s]; }
    __syncthreads();
  }
  if (tid==0){
    float n = (float)(B_*LL);
    float m = ss[0]/n, v = sq[0]/n - m*m;
    float s = rsqrtf(v + EPSI) * g[f];
    ws[O_S1 + f]       = s;
    ws[O_S1 + NFC + f] = bt[f] - m*s;
  }
}

// ---------- pack fcw*s1[f] into B-frag layout + cvec, fused ----------
__global__ void k_fcwp_cvec(const float* __restrict__ fcw, const float* __restrict__ fcb,
                            float* __restrict__ ws){
  __shared__ float shm[256];
  int blk = blockIdx.x;
  if (blk < 768){
    int s = blk*256 + threadIdx.x;   // 196608 slots
    int lane = s & 63;
    int ks = (s >> 6) % YKS;
    int ntile = (s >> 6) / YKS;
    int n = ntile*16 + (lane & 15);         // < 256
    int k0 = ks*32 + (lane >> 4)*8;         // < 6144
    int f = (k0 >> 6) / 3;                  // k0/192
    float sc = ws[O_S1 + f];
    unsigned short o8[8];
    if (n < DE){
      const float* p = fcw + (size_t)n*FCLEN + k0;
      float4 f0 = *(const float4*)p;
      float4 f1 = *(const float4*)(p + 4);
      o8[0]=f2bf(f0.x*sc); o8[1]=f2bf(f0.y*sc); o8[2]=f2bf(f0.z*sc); o8[3]=f2bf(f0.w*sc);
      o8[4]=f2bf(f1.x*sc); o8[5]=f2bf(f1.y*sc); o8[6]=f2bf(f1.z*sc); o8[7]=f2bf(f1.w*sc);
    } else {
      #pragma unroll
      for (int j = 0; j < 8; ++j) o8[j] = 0;
    }
    *(bf16x8*)((unsigned short*)(ws + O_FCWP) + (size_t)s*8) = *(bf16x8*)o8;
  } else {
    // cvec: c[o] = sum_i t1[f(i)]*fcw[o,i] + fc_b[o]
    __shared__ float t1s[NFC];
    int o = blk - 768, tid = threadIdx.x;
    if (tid < NFC) t1s[tid] = ws[O_S1 + NFC + tid];
    __syncthreads();
    float acc = 0.f;
    for (int i = tid; i < FCLEN; i += 256)
      acc += fcw[(size_t)o*FCLEN + i] * t1s[i/LL];
    shm[tid] = acc; __syncthreads();
    for (int s=128; s>0; s>>=1){
      if (tid < s) shm[tid] += shm[tid+s];
      __syncthreads();
    }
    if (tid==0) ws[O_CVEC + o] = shm[0] + fcb[o];
  }
}

// ---------- y-GEMM via MFMA, both sides frag-coalesced, 16-way K-split ----------
__global__ __launch_bounds__(256) void k_ygemm_m(float* __restrict__ ws){
  const unsigned short* Cb = (const unsigned short*)(ws + O_CFRAG);
  const unsigned short* Wb = (const unsigned short*)(ws + O_FCWP);
  int mt = blockIdx.x;      // 0..15
  int seg = blockIdx.y;     // 0..15
  int tid = threadIdx.x;
  int lane = tid & 63, wid = tid >> 6;
  int lr = lane & 15, lg = lane >> 4;
  f32x4 acc[4][4] = {};     // [mf][nf], nt = wid*4+nf
  #pragma unroll 4
  for (int ksl = 0; ksl < 12; ++ksl){
    int ks = seg*12 + ksl;
    bf16x8 a[4], bfr[4];
    #pragma unroll
    for (int mf = 0; mf < 4; ++mf)
      a[mf] = *(const bf16x8*)(Cb + ((size_t)((mt*4+mf)*YKS + ks)*64 + lane)*8);
    #pragma unroll
    for (int nf = 0; nf < 4; ++nf){
      int nt = wid*4 + nf;
      bfr[nf] = *(const bf16x8*)(Wb + ((size_t)(nt*YKS + ks)*64 + lane)*8);
    }
    #pragma unroll
    for (int mf = 0; mf < 4; ++mf)
      #pragma unroll
      for (int nf = 0; nf < 4; ++nf)
        acc[mf][nf] = __builtin_amdgcn_mfma_f32_16x16x32_bf16(a[mf], bfr[nf], acc[mf][nf], 0, 0, 0);
  }
  float* part = ws + O_PART + (size_t)seg*(B_*DE);
  #pragma unroll
  for (int nf = 0; nf < 4; ++nf){
    int col = (wid*4 + nf)*16 + lr;
    if (col < DE){
      #pragma unroll
      for (int mf = 0; mf < 4; ++mf){
        int row = mt*64 + mf*16 + lg*4;
        #pragma unroll
        for (int r = 0; r < 4; ++r)
          part[(size_t)(row + r)*DE + col] = acc[mf][nf][r];
      }
    }
  }
}

__global__ void k_yreduce(float* __restrict__ ws){
  int i = blockIdx.x*256 + threadIdx.x;   // 204800
  int o = i % DE;
  float y = ws[O_CVEC + o];
  #pragma unroll
  for (int s = 0; s < YSEG; ++s) y += ws[O_PART + (size_t)s*(B_*DE) + i];
  ws[O_Y + i] = y;
}

// ---------- BN2 stats ----------
__global__ void k_bn2(const float* __restrict__ g, const float* __restrict__ bt,
                      float* __restrict__ ws){
  __shared__ float ss[256], sq[256];
  int o = blockIdx.x, tid = threadIdx.x;
  float a = 0.f, b = 0.f;
  for (int i = tid; i < B_; i += 256){
    float v = ws[O_Y + i*DE + o];
    a += v; b += v*v;
  }
  ss[tid]=a; sq[tid]=b; __syncthreads();
  for (int s=128; s>0; s>>=1){
    if (tid < s){ ss[tid]+=ss[tid+s]; sq[tid]+=sq[tid+s]; }
    __syncthreads();
  }
  if (tid==0){
    float n = (float)B_;
    float m = ss[0]/n, v = sq[0]/n - m*m;
    float s = rsqrtf(v + EPSI) * g[o];
    ws[O_S2 + o]      = s;
    ws[O_S2 + DE + o] = bt[o] - m*s;
  }
}

// ---------- BN2-apply + ReLU + bf16 A-frags ----------
__global__ void k_abf(float* __restrict__ ws){
  int s = blockIdx.x*256 + threadIdx.x;   // 28672 slots exact
  int lane = s & 63;
  int ks = (s >> 6) % NKS;
  int mtile = (s >> 6) / NKS;
  int m = mtile*16 + (lane & 15);
  int k0 = ks*32 + (lane >> 4)*8;
  unsigned short o8[8];
  #pragma unroll
  for (int j = 0; j < 8; ++j){
    int k = k0 + j;
    float v = 0.f;
    if (k < DE){
      float y = ws[O_Y + m*DE + k];
      v = fmaxf(y*ws[O_S2 + k] + ws[O_S2 + DE + k], 0.f);
    }
    o8[j] = f2bf(v);
  }
  *(bf16x8*)((unsigned short*)(ws + O_ABF) + (size_t)s*8) = *(bf16x8*)o8;
}

// ---------- scores GEMM (r10 config): one block per 256-col stripe, all 1024 rows,
// NT E-loads (single reader), LDS-transpose epilogue, 1KB NT row stores ----------
__global__ __launch_bounds__(256, 2) void k_scores(const float* __restrict__ E,
                                                   const float* __restrict__ bias,
                                                   const float* __restrict__ ws,
                                                   float* __restrict__ out){
  __shared__ float tile[64*256];          // 64 KB
  const unsigned short* Abf = (const unsigned short*)(ws + O_ABF);
  int ns = blockIdx.x;                    // 0..390
  int tid = threadIdx.x;
  int lane = tid & 63, wid = tid >> 6;
  int lr = lane & 15, lg = lane >> 4;

  // ---- E resident: 4 n-tiles x 7 ks, fp32 -> bf16 once (nontemporal reads) ----
  bf16x8 ebf[4][7];
  float bv[4];
  #pragma unroll
  for (int nf = 0; nf < 4; ++nf){
    int col = ns*256 + wid*64 + nf*16 + lr;
    int nc = (col < NENT) ? col : (NENT-1);
    bv[nf] = bias[nc];
    const float* ep = E + (size_t)nc*DE;
    #pragma unroll
    for (int ks = 0; ks < NKS; ++ks){
      int k0 = ks*32 + lg*8;
      if (k0 + 8 <= DE){
        f32x4 f0 = __builtin_nontemporal_load((const f32x4*)(ep + k0));
        f32x4 f1 = __builtin_nontemporal_load((const f32x4*)(ep + k0 + 4));
        ebf[nf][ks] = pack8v(f0, f1);
      } else {
        ebf[nf][ks] = (bf16x8){0,0,0,0,0,0,0,0};
      }
    }
  }

  const unsigned short* aBase = Abf + lane*8;
  int col0 = ns*256;
  #pragma unroll 1
  for (int t = 0; t < 16; ++t){
    const unsigned short* ap = aBase + (size_t)t*1792*8;
    bf16x8 aC[4], aN[4];
    #pragma unroll
    for (int mf = 0; mf < 4; ++mf) aC[mf] = *(const bf16x8*)(ap + (size_t)(mf*NKS)*512);
    f32x4 acc[4][4] = {};
    #pragma unroll
    for (int ks = 0; ks < NKS; ++ks){
      if (ks < NKS-1){
        #pragma unroll
        for (int mf = 0; mf < 4; ++mf)
          aN[mf] = *(const bf16x8*)(ap + (size_t)(mf*NKS + ks + 1)*512);
      }
      #pragma unroll
      for (int mf = 0; mf < 4; ++mf)
        #pragma unroll
        for (int nf = 0; nf < 4; ++nf)
          acc[mf][nf] = __builtin_amdgcn_mfma_f32_16x16x32_bf16(aC[mf], ebf[nf][ks], acc[mf][nf], 0, 0, 0);
      #pragma unroll
      for (int mf = 0; mf < 4; ++mf) aC[mf] = aN[mf];
    }
    // ---- epilogue: sigmoid -> LDS [64 rows][256 cols] ----
    __syncthreads();                       // previous iteration's reads done
    #pragma unroll
    for (int mf = 0; mf < 4; ++mf)
      #pragma unroll
      for (int nf = 0; nf < 4; ++nf){
        int lrow = mf*16 + lg*4;
        int lcol = wid*64 + nf*16 + lr;
        #pragma unroll
        for (int r = 0; r < 4; ++r)
          tile[(lrow + r)*256 + lcol] = sigm(acc[mf][nf][r] + bv[nf]);
      }
    __syncthreads();
    // ---- wave-wide 1KB contiguous nt stores ----
    int row0 = t*64;
    #pragma unroll
    for (int p = 0; p < 16; ++p){
      int lrow = p*4 + wid;
      int lcol = lane*4;
      f32x4 v = *(const f32x4*)&tile[lrow*256 + lcol];
      int gc = col0 + lcol;
      if (gc < NENT)
        __builtin_nontemporal_store(v, (f32x4*)&out[(size_t)(row0 + lrow)*NENT + gc]);
    }
  }
}

extern "C" void kernel_launch(void* const* d_in, const int* in_sizes, int n_in,
                              void* d_out, int out_size, void* d_ws, size_t ws_size,
                              hipStream_t stream){
  (void)in_sizes; (void)n_in; (void)out_size; (void)ws_size;
  const float* e1    = (const float*)d_in[0];
  const float* r     = (const float*)d_in[1];
  const float* fc1_w = (const float*)d_in[2];
  const float* fc1_b = (const float*)d_in[3];
  const float* fc_w  = (const float*)d_in[4];
  const float* fc_b  = (const float*)d_in[5];
  const float* E     = (const float*)d_in[6];
  const float* bE    = (const float*)d_in[7];
  const float* g0    = (const float*)d_in[8];
  const float* b0    = (const float*)d_in[9];
  const float* g1    = (const float*)d_in[10];
  const float* b1    = (const float*)d_in[11];
  const float* g2    = (const float*)d_in[12];
  const float* b2    = (const float*)d_in[13];
  float* ws  = (float*)d_ws;
  float* out = (float*)d_out;

  k_pack0     <<<208, 256, 0, stream>>>(r, fc1_w, e1, ws);
  k_fc1m      <<<dim3(16,19), 64, 0, stream>>>(fc1_b, g0, b0, ws);
  k_conv      <<<1024,256, 0, stream>>>(e1, ws);
  k_bn1_final <<<32,  256, 0, stream>>>(g1, b1, ws);
  k_fcwp_cvec <<<968, 256, 0, stream>>>(fc_w, fc_b, ws);
  k_ygemm_m   <<<dim3(16,16), 256, 0, stream>>>(ws);
  k_yreduce   <<<800, 256, 0, stream>>>(ws);
  k_bn2       <<<200, 256, 0, stream>>>(g2, b2, ws);
  k_abf       <<<112, 256, 0, stream>>>(ws);
  k_scores    <<<391, 256, 0, stream>>>(E, bE, ws, out);
}